// Round 1
// baseline (433.709 us; speedup 1.0000x reference)
//
#include <hip/hip_runtime.h>

#define KK 32
#define FF 32
#define EE 20

// One thread per edge. Block 256 threads = 8 nodes x 32 edges.
// Weights are read via lane-uniform indices -> scalar loads (s_load),
// so weight fetch costs no VALU slots and no LDS.
__global__ __launch_bounds__(256) void deepdft_msg_kernel(
    const float* __restrict__ S,     // [N,K,1,F]
    const float* __restrict__ V,     // [N,K,3,F]
    const float* __restrict__ EXPN,  // [N,K,E]
    const float* __restrict__ DIR,   // [N,K,3]
    const float* __restrict__ MASK,  // [N,K,1]
    const float* __restrict__ DIST,  // [N,K,1]
    const float* __restrict__ W1,    // [F,F]
    const float* __restrict__ B1,    // [F]
    const float* __restrict__ W2,    // [F,3F]
    const float* __restrict__ B2,    // [3F]
    const float* __restrict__ WR,    // [E,3F]
    const float* __restrict__ BR,    // [3F]
    float* __restrict__ OUT,         // delta_s [N,1,F] ++ delta_v [N,3,F]
    int n_nodes)
{
    const int t = blockIdx.x * 256 + threadIdx.x;   // edge id
    const int n = t >> 5;                           // node
    if (n >= n_nodes) return;
    const int lane32 = threadIdx.x & 31;

    // per-edge gate scalar: mask * cosine_cutoff(dist)
    const float dist = DIST[t];
    float w = MASK[t];
    float fc = 0.0f;
    if (dist < 5.0f) fc = 0.5f * (__cosf(0.628318530717958648f * dist) + 1.0f);
    w *= fc;

    // ---- load s row (coalesced float4) ----
    float sr[FF];
    {
        const float4* p = reinterpret_cast<const float4*>(S + (size_t)t * FF);
        #pragma unroll
        for (int j = 0; j < FF / 4; ++j) {
            float4 q = p[j];
            sr[4*j+0] = q.x; sr[4*j+1] = q.y; sr[4*j+2] = q.z; sr[4*j+3] = q.w;
        }
    }

    // ---- h = silu(s @ W1 + b1) ----
    float h[FF];
    #pragma unroll
    for (int f = 0; f < FF; ++f) h[f] = B1[f];
    #pragma unroll
    for (int i = 0; i < FF; ++i) {
        const float si = sr[i];
        const float* wrow = W1 + i * FF;   // uniform -> s_load
        #pragma unroll
        for (int f = 0; f < FF; ++f) h[f] = fmaf(si, wrow[f], h[f]);
    }
    #pragma unroll
    for (int f = 0; f < FF; ++f) h[f] = h[f] / (1.0f + __expf(-h[f]));

    // ---- expansion row, pre-scaled by w (folds mask*f_cut into right branch) ----
    float er[EE];
    {
        const float4* p = reinterpret_cast<const float4*>(EXPN + (size_t)t * EE);
        #pragma unroll
        for (int j = 0; j < EE / 4; ++j) {
            float4 q = p[j];
            er[4*j+0] = q.x * w; er[4*j+1] = q.y * w; er[4*j+2] = q.z * w; er[4*j+3] = q.w * w;
        }
    }

    const float dx = DIR[t*3+0], dy = DIR[t*3+1], dz = DIR[t*3+2];

    float* outS = OUT + (size_t)n * FF;
    float* outV = OUT + (size_t)n_nodes * FF + (size_t)n * 3 * FF;

    // ---- 4 chunks of 8 features, each covering the (a,b,c) triplet ----
    #pragma unroll 1
    for (int cg = 0; cg < 4; ++cg) {
        const int g0 = cg * 8;

        // left = silu(...) @ W2 + b2, three 8-wide slices (a,b,c)
        float la[8], lb[8], lc[8];
        #pragma unroll
        for (int j = 0; j < 8; ++j) {
            la[j] = B2[g0 + j]; lb[j] = B2[32 + g0 + j]; lc[j] = B2[64 + g0 + j];
        }
        #pragma unroll
        for (int i = 0; i < FF; ++i) {
            const float hi = h[i];
            const float* wrow = W2 + i * 96 + g0;  // uniform -> s_load
            #pragma unroll
            for (int j = 0; j < 8; ++j) la[j] = fmaf(hi, wrow[j],      la[j]);
            #pragma unroll
            for (int j = 0; j < 8; ++j) lb[j] = fmaf(hi, wrow[32 + j], lb[j]);
            #pragma unroll
            for (int j = 0; j < 8; ++j) lc[j] = fmaf(hi, wrow[64 + j], lc[j]);
        }

        // right = w * (expansion @ Wr + br)  (w already folded into er / bias)
        float ra[8], rb[8], rc[8];
        #pragma unroll
        for (int j = 0; j < 8; ++j) {
            ra[j] = w * BR[g0 + j]; rb[j] = w * BR[32 + g0 + j]; rc[j] = w * BR[64 + g0 + j];
        }
        #pragma unroll
        for (int i = 0; i < EE; ++i) {
            const float ei = er[i];
            const float* wrow = WR + i * 96 + g0;  // uniform -> s_load
            #pragma unroll
            for (int j = 0; j < 8; ++j) ra[j] = fmaf(ei, wrow[j],      ra[j]);
            #pragma unroll
            for (int j = 0; j < 8; ++j) rb[j] = fmaf(ei, wrow[32 + j], rb[j]);
            #pragma unroll
            for (int j = 0; j < 8; ++j) rc[j] = fmaf(ei, wrow[64 + j], rc[j]);
        }

        // v chunk loads (float4, aligned: 384/128/32 all multiples of 16B)
        float vv0[8], vv1[8], vv2[8];
        {
            const float* vb = V + (size_t)t * 96 + g0;
            const float4* p0 = reinterpret_cast<const float4*>(vb);
            const float4* p1 = reinterpret_cast<const float4*>(vb + 32);
            const float4* p2 = reinterpret_cast<const float4*>(vb + 64);
            float4 q;
            q = p0[0]; vv0[0]=q.x; vv0[1]=q.y; vv0[2]=q.z; vv0[3]=q.w;
            q = p0[1]; vv0[4]=q.x; vv0[5]=q.y; vv0[6]=q.z; vv0[7]=q.w;
            q = p1[0]; vv1[0]=q.x; vv1[1]=q.y; vv1[2]=q.z; vv1[3]=q.w;
            q = p1[1]; vv1[4]=q.x; vv1[5]=q.y; vv1[6]=q.z; vv1[7]=q.w;
            q = p2[0]; vv2[0]=q.x; vv2[1]=q.y; vv2[2]=q.z; vv2[3]=q.w;
            q = p2[1]; vv2[4]=q.x; vv2[5]=q.y; vv2[6]=q.z; vv2[7]=q.w;
        }

        // gated contributions (already masked via w in right branch)
        float cs[8], cv0[8], cv1[8], cv2[8];
        #pragma unroll
        for (int j = 0; j < 8; ++j) {
            const float ga = la[j] * ra[j];
            const float gc = lc[j] * rc[j];
            cs[j]  = lb[j] * rb[j];
            cv0[j] = fmaf(vv0[j], ga, dx * gc);
            cv1[j] = fmaf(vv1[j], ga, dy * gc);
            cv2[j] = fmaf(vv2[j], ga, dz * gc);
        }

        // reduce over the 32 edges of this node (5-step butterfly, width 32)
        #pragma unroll
        for (int off = 1; off < 32; off <<= 1) {
            #pragma unroll
            for (int j = 0; j < 8; ++j) {
                cs[j]  += __shfl_xor(cs[j],  off, 32);
                cv0[j] += __shfl_xor(cv0[j], off, 32);
                cv1[j] += __shfl_xor(cv1[j], off, 32);
                cv2[j] += __shfl_xor(cv2[j], off, 32);
            }
        }

        if (lane32 == 0) {
            *reinterpret_cast<float4*>(outS + g0)     = make_float4(cs[0], cs[1], cs[2], cs[3]);
            *reinterpret_cast<float4*>(outS + g0 + 4) = make_float4(cs[4], cs[5], cs[6], cs[7]);
            *reinterpret_cast<float4*>(outV + g0)          = make_float4(cv0[0], cv0[1], cv0[2], cv0[3]);
            *reinterpret_cast<float4*>(outV + g0 + 4)      = make_float4(cv0[4], cv0[5], cv0[6], cv0[7]);
            *reinterpret_cast<float4*>(outV + 32 + g0)     = make_float4(cv1[0], cv1[1], cv1[2], cv1[3]);
            *reinterpret_cast<float4*>(outV + 32 + g0 + 4) = make_float4(cv1[4], cv1[5], cv1[6], cv1[7]);
            *reinterpret_cast<float4*>(outV + 64 + g0)     = make_float4(cv2[0], cv2[1], cv2[2], cv2[3]);
            *reinterpret_cast<float4*>(outV + 64 + g0 + 4) = make_float4(cv2[4], cv2[5], cv2[6], cv2[7]);
        }
    }
}

extern "C" void kernel_launch(void* const* d_in, const int* in_sizes, int n_in,
                              void* d_out, int out_size, void* d_ws, size_t ws_size,
                              hipStream_t stream) {
    const float* S    = (const float*)d_in[0];
    const float* V    = (const float*)d_in[1];
    const float* EXPN = (const float*)d_in[2];
    const float* DIR  = (const float*)d_in[3];
    const float* MASK = (const float*)d_in[4];
    const float* DIST = (const float*)d_in[5];
    const float* W1   = (const float*)d_in[6];
    const float* B1   = (const float*)d_in[7];
    const float* W2   = (const float*)d_in[8];
    const float* B2   = (const float*)d_in[9];
    const float* WR   = (const float*)d_in[10];
    const float* BR   = (const float*)d_in[11];
    float* OUT = (float*)d_out;

    const int n_nodes = in_sizes[0] / (KK * FF);   // 30000
    const int edges = n_nodes * KK;                // 960000
    const int grid = (edges + 255) / 256;          // 3750

    hipLaunchKernelGGL(deepdft_msg_kernel, dim3(grid), dim3(256), 0, stream,
                       S, V, EXPN, DIR, MASK, DIST, W1, B1, W2, B2, WR, BR,
                       OUT, n_nodes);
}

// Round 2
// 215.610 us; speedup vs baseline: 2.0115x; 2.0115x over previous
//
#include <hip/hip_runtime.h>

typedef __attribute__((ext_vector_type(8))) short bf16x8;
typedef __attribute__((ext_vector_type(4))) float f32x4;

#define NPB 16   // nodes per block (4 waves x 4 nodes)

__device__ __forceinline__ short f2bf(float f) {
  unsigned u = __float_as_uint(f);
  u += 0x7fffu + ((u >> 16) & 1u);   // RNE to bf16
  return (short)(u >> 16);
}

__device__ __forceinline__ bf16x8 ldsfrag(const int* p) {
  union { int4 i; bf16x8 b; } u;
  u.i = *reinterpret_cast<const int4*>(p);
  return u.b;
}

// One wave per node (32 edges = 2 x 16-row A tiles).
// All three matmuls via mfma_f32_16x16x32_bf16; weights staged once per
// block into LDS in B-fragment layout (lane l holds B[8*(l>>4)+j][l&15]).
// A-frag: lane l holds A[l&15][8*(l>>4)+j] — same claimed-k mapping on both
// sides, so correctness is invariant to the hardware's internal k order.
// D layout (verified): col=lane&15, row=4*(lane>>4)+reg.
__global__ __launch_bounds__(256) void deepdft_mfma(
    const float* __restrict__ S,     // [N,K,1,32]
    const float* __restrict__ V,     // [N,K,3,32]
    const float* __restrict__ EXPN,  // [N,K,20]
    const float* __restrict__ DIR,   // [N,K,3]
    const float* __restrict__ MASK,  // [N,K,1]
    const float* __restrict__ DIST,  // [N,K,1]
    const float* __restrict__ W1,    // [32,32]
    const float* __restrict__ B1,    // [32]
    const float* __restrict__ W2,    // [32,96]
    const float* __restrict__ B2,    // [96]
    const float* __restrict__ WR,    // [20,96]
    const float* __restrict__ BR,    // [96]
    float* __restrict__ OUT,         // [N,1,32] ++ [N,3,32]
    int n_nodes)
{
  __shared__ int   wlds[14][256];     // 14 B-frag tiles x 64 lanes x 16B
  __shared__ float hbuf[4][16][36];   // per-wave h round-trip, pad 36

  const int tid = threadIdx.x;
  const int wid = tid >> 6;
  const int l   = tid & 63;
  const int col16 = l & 15;
  const int c  = l >> 4;
  const int kc = c << 3;

  // ---- stage weight B-fragments (bf16) into LDS, split across waves ----
  for (int t = wid; t < 14; t += 4) {
    const float* src; int rs, co, kl;
    if (t < 2)      { src = W1; rs = 32; co = t << 4;       kl = 32; }
    else if (t < 8) { src = W2; rs = 96; co = (t - 2) << 4; kl = 32; }
    else            { src = WR; rs = 96; co = (t - 8) << 4; kl = 20; }
    int q[4];
    #pragma unroll
    for (int jj = 0; jj < 4; ++jj) {
      int k0 = kc + 2 * jj;
      float f0 = (k0     < kl) ? src[(k0    ) * rs + co + col16] : 0.f;
      float f1 = (k0 + 1 < kl) ? src[(k0 + 1) * rs + co + col16] : 0.f;
      q[jj] = ((int)(unsigned short)f2bf(f0)) |
              (((int)(unsigned short)f2bf(f1)) << 16);
    }
    *reinterpret_cast<int4*>(&wlds[t][l << 2]) = make_int4(q[0], q[1], q[2], q[3]);
  }

  // per-lane biases (held in regs for the whole kernel)
  const float b1v0 = B1[col16], b1v1 = B1[16 + col16];
  float b2v[6], brv[6];
  #pragma unroll
  for (int t = 0; t < 6; ++t) {
    b2v[t] = B2[(t << 4) + col16];
    brv[t] = BR[(t << 4) + col16];
  }

  __syncthreads();

  const bf16x8 w1f0 = ldsfrag(&wlds[0][l << 2]);
  const bf16x8 w1f1 = ldsfrag(&wlds[1][l << 2]);

  #pragma unroll 1
  for (int i = 0; i < 4; ++i) {
    const int n = blockIdx.x * NPB + (wid << 2) + i;
    if (n >= n_nodes) break;

    float acc[8] = {0.f,0.f,0.f,0.f,0.f,0.f,0.f,0.f}; // s0,s1,v00,v01,v10,v11,v20,v21

    #pragma unroll 1
    for (int eg = 0; eg < 2; ++eg) {
      const int ebase = (n << 5) + (eg << 4);
      const int arow  = ebase + col16;

      // ---- A_s fragment: lane reads s[arow][kc..kc+7] ----
      const float* sp = S + (size_t)arow * 32 + kc;
      float4 s0 = *reinterpret_cast<const float4*>(sp);
      float4 s1 = *reinterpret_cast<const float4*>(sp + 4);
      bf16x8 as;
      as[0]=f2bf(s0.x); as[1]=f2bf(s0.y); as[2]=f2bf(s0.z); as[3]=f2bf(s0.w);
      as[4]=f2bf(s1.x); as[5]=f2bf(s1.y); as[6]=f2bf(s1.z); as[7]=f2bf(s1.w);

      // ---- h = silu(s @ W1 + b1) ----
      f32x4 h0 = {b1v0, b1v0, b1v0, b1v0};
      f32x4 h1 = {b1v1, b1v1, b1v1, b1v1};
      h0 = __builtin_amdgcn_mfma_f32_16x16x32_bf16(as, w1f0, h0, 0, 0, 0);
      h1 = __builtin_amdgcn_mfma_f32_16x16x32_bf16(as, w1f1, h1, 0, 0, 0);
      #pragma unroll
      for (int r = 0; r < 4; ++r) {
        float x0 = h0[r]; x0 = __fdividef(x0, 1.f + __expf(-x0));
        float x1 = h1[r]; x1 = __fdividef(x1, 1.f + __expf(-x1));
        hbuf[wid][(c << 2) + r][col16]      = x0;   // D row = 4c+r, col = col16
        hbuf[wid][(c << 2) + r][16 + col16] = x1;
      }

      // ---- A_e fragment (expansion, K padded 20->32) ----
      const float* ep = EXPN + (size_t)arow * 20;
      float ev[8];
      #pragma unroll
      for (int j = 0; j < 8; ++j) ev[j] = 0.f;
      if (kc < 20) {
        float4 e0 = *reinterpret_cast<const float4*>(ep + kc);
        ev[0]=e0.x; ev[1]=e0.y; ev[2]=e0.z; ev[3]=e0.w;
      }
      if (kc + 4 < 20) {
        float4 e1 = *reinterpret_cast<const float4*>(ep + kc + 4);
        ev[4]=e1.x; ev[5]=e1.y; ev[6]=e1.z; ev[7]=e1.w;
      }
      bf16x8 ae;
      #pragma unroll
      for (int j = 0; j < 8; ++j) ae[j] = f2bf(ev[j]);

      // ---- right = expansion @ Wr + br (6 col-tiles) ----
      f32x4 right[6];
      #pragma unroll
      for (int t = 0; t < 6; ++t) {
        f32x4 ci = {brv[t], brv[t], brv[t], brv[t]};
        right[t] = __builtin_amdgcn_mfma_f32_16x16x32_bf16(
            ae, ldsfrag(&wlds[8 + t][l << 2]), ci, 0, 0, 0);
      }

      // ---- h D-layout -> A-layout via per-wave LDS (wave-internal) ----
      __builtin_amdgcn_wave_barrier();          // writes above stay above
      const float* hp = &hbuf[wid][col16][kc];
      float4 hh0 = *reinterpret_cast<const float4*>(hp);
      float4 hh1 = *reinterpret_cast<const float4*>(hp + 4);
      __builtin_amdgcn_wave_barrier();          // next eg's writes stay below
      bf16x8 ah;
      ah[0]=f2bf(hh0.x); ah[1]=f2bf(hh0.y); ah[2]=f2bf(hh0.z); ah[3]=f2bf(hh0.w);
      ah[4]=f2bf(hh1.x); ah[5]=f2bf(hh1.y); ah[6]=f2bf(hh1.z); ah[7]=f2bf(hh1.w);

      // ---- left = h @ W2 + b2 (6 col-tiles) ----
      f32x4 left[6];
      #pragma unroll
      for (int t = 0; t < 6; ++t) {
        f32x4 ci = {b2v[t], b2v[t], b2v[t], b2v[t]};
        left[t] = __builtin_amdgcn_mfma_f32_16x16x32_bf16(
            ah, ldsfrag(&wlds[2 + t][l << 2]), ci, 0, 0, 0);
      }

      // ---- gating + v/dir contraction, accumulate over edges ----
      const int g4 = c << 2;
      #pragma unroll
      for (int r = 0; r < 4; ++r) {
        const int er = ebase + g4 + r;          // D row = edge
        const float dist = DIST[er];
        const float mk   = MASK[er];
        float w = 0.f;
        if (dist < 5.f) w = mk * 0.5f * (__cosf(0.62831853071795865f * dist) + 1.f);
        const float dx = DIR[er * 3 + 0];
        const float dy = DIR[er * 3 + 1];
        const float dz = DIR[er * 3 + 2];
        #pragma unroll
        for (int t = 0; t < 2; ++t) {
          const float ga = w * left[t][r]     * right[t][r];
          const float gb = w * left[2 + t][r] * right[2 + t][r];
          const float gc = w * left[4 + t][r] * right[4 + t][r];
          acc[t] += gb;
          const float* vp = V + (size_t)er * 96 + (t << 4) + col16;
          acc[2 + t] = fmaf(vp[0],  ga, fmaf(dx, gc, acc[2 + t]));
          acc[4 + t] = fmaf(vp[32], ga, fmaf(dy, gc, acc[4 + t]));
          acc[6 + t] = fmaf(vp[64], ga, fmaf(dz, gc, acc[6 + t]));
        }
      }
    }

    // ---- reduce over lane groups (edges live on regs + l>>4) ----
    #pragma unroll
    for (int q = 0; q < 8; ++q) {
      acc[q] += __shfl_xor(acc[q], 16);
      acc[q] += __shfl_xor(acc[q], 32);
    }
    if (l < 16) {
      float* os = OUT + (size_t)n * 32;
      os[col16]      = acc[0];
      os[16 + col16] = acc[1];
      float* ov = OUT + (size_t)n_nodes * 32 + (size_t)n * 96;
      ov[     col16] = acc[2]; ov[16 + col16] = acc[3];
      ov[32 + col16] = acc[4]; ov[48 + col16] = acc[5];
      ov[64 + col16] = acc[6]; ov[80 + col16] = acc[7];
    }
  }
}

extern "C" void kernel_launch(void* const* d_in, const int* in_sizes, int n_in,
                              void* d_out, int out_size, void* d_ws, size_t ws_size,
                              hipStream_t stream) {
  const float* S    = (const float*)d_in[0];
  const float* V    = (const float*)d_in[1];
  const float* EXPN = (const float*)d_in[2];
  const float* DIR  = (const float*)d_in[3];
  const float* MASK = (const float*)d_in[4];
  const float* DIST = (const float*)d_in[5];
  const float* W1   = (const float*)d_in[6];
  const float* B1   = (const float*)d_in[7];
  const float* W2   = (const float*)d_in[8];
  const float* B2   = (const float*)d_in[9];
  const float* WR   = (const float*)d_in[10];
  const float* BR   = (const float*)d_in[11];
  float* OUT = (float*)d_out;

  const int n_nodes = in_sizes[0] / 1024;            // 30000
  const int grid = (n_nodes + NPB - 1) / NPB;        // 1875

  hipLaunchKernelGGL(deepdft_mfma, dim3(grid), dim3(256), 0, stream,
                     S, V, EXPN, DIR, MASK, DIST, W1, B1, W2, B2, WR, BR,
                     OUT, n_nodes);
}

// Round 3
// 145.347 us; speedup vs baseline: 2.9840x; 1.4834x over previous
//
#include <hip/hip_runtime.h>

typedef __attribute__((ext_vector_type(8))) short bf16x8;
typedef __attribute__((ext_vector_type(4))) float f32x4;

#define NPB 16   // nodes per block (4 waves x 4 nodes)

__device__ __forceinline__ short f2bf(float f) {
  unsigned u = __float_as_uint(f);
  u += 0x7fffu + ((u >> 16) & 1u);   // RNE to bf16
  return (short)(u >> 16);
}

__device__ __forceinline__ bf16x8 ldsfrag(const int* p) {
  union { int4 i; bf16x8 b; } u;
  u.i = *reinterpret_cast<const int4*>(p);
  return u.b;
}

// One wave per node (32 edges = 2 x 16-row tiles).
// hT = A(W1^T tile) * B(s^T): B-frag(s^T) == A-frag(s) per-lane, so the s load
// is unchanged; D leaves lane(c,col16) holding h[edge=col16][feat 4c+r] /
// [16+4c+r] — i.e. a ready A-frag of h under k-permutation pi(c,j) =
// (j<4 ? 4c+j : 16+4c+j-4), which is folded into the W2 LDS staging.
// MFMA is invariant to a k-relabeling applied to BOTH operands.
// Right-branch bias rides in the spare k=20 slot of the padded expansion.
__global__ __launch_bounds__(256) void deepdft_v3(
    const float* __restrict__ S,     // [N,K,1,32]
    const float* __restrict__ V,     // [N,K,3,32]
    const float* __restrict__ EXPN,  // [N,K,20]
    const float* __restrict__ DIR,   // [N,K,3]
    const float* __restrict__ MASK,  // [N,K,1]
    const float* __restrict__ DIST,  // [N,K,1]
    const float* __restrict__ W1,    // [32,32]
    const float* __restrict__ B1,    // [32]
    const float* __restrict__ W2,    // [32,96]
    const float* __restrict__ B2,    // [96]
    const float* __restrict__ WR,    // [20,96]
    const float* __restrict__ BR,    // [96]
    float* __restrict__ OUT,         // [N,1,32] ++ [N,3,32]
    int n_nodes)
{
  __shared__ int wlds[14][256];   // 14 fragment tiles x 64 lanes x 16B

  const int tid = threadIdx.x, wid = tid >> 6, l = tid & 63;
  const int col16 = l & 15, c = l >> 4, kc = c << 3;

  // ---- stage weight fragments (bf16) into LDS, split across waves ----
  for (int t = wid; t < 14; t += 4) {
    int q[4];
    #pragma unroll
    for (int jj = 0; jj < 4; ++jj) {
      float f0, f1;
      if (t < 2) {                       // W1^T A-frag (== W1 B-frag data)
        int k0 = kc + 2*jj;
        int co = (t << 4) + col16;
        f0 = W1[k0*32 + co]; f1 = W1[(k0+1)*32 + co];
      } else if (t < 8) {                // W2 B-frag, k permuted by pi(c,j)
        int j0 = 2*jj;
        int feat = (j0 < 4) ? (4*c + j0) : (16 + 4*c + (j0 - 4));
        int co = ((t-2) << 4) + col16;
        f0 = W2[feat*96 + co]; f1 = W2[(feat+1)*96 + co];
      } else {                           // WR B-frag, row20 = BR (bias), rest 0
        int k0 = kc + 2*jj;
        int co = ((t-8) << 4) + col16;
        f0 = (k0   < 20) ? WR[k0*96 + co]     : ((k0   == 20) ? BR[co] : 0.f);
        f1 = (k0+1 < 20) ? WR[(k0+1)*96 + co] : ((k0+1 == 20) ? BR[co] : 0.f);
      }
      q[jj] = ((int)(unsigned short)f2bf(f0)) |
              (((int)(unsigned short)f2bf(f1)) << 16);
    }
    *reinterpret_cast<int4*>(&wlds[t][l << 2]) = make_int4(q[0], q[1], q[2], q[3]);
  }

  // b1 per-lane (feature = 16t + 4c + r), b2 per-lane scalars
  f32x4 b1a, b1b;
  {
    float4 t0 = *reinterpret_cast<const float4*>(B1 + 4*c);
    float4 t1 = *reinterpret_cast<const float4*>(B1 + 16 + 4*c);
    b1a[0]=t0.x; b1a[1]=t0.y; b1a[2]=t0.z; b1a[3]=t0.w;
    b1b[0]=t1.x; b1b[1]=t1.y; b1b[2]=t1.z; b1b[3]=t1.w;
  }
  float b2v[6];
  #pragma unroll
  for (int t = 0; t < 6; ++t) b2v[t] = B2[(t << 4) + col16];

  __syncthreads();

  const bf16x8 w1a0 = ldsfrag(&wlds[0][l << 2]);
  const bf16x8 w1a1 = ldsfrag(&wlds[1][l << 2]);

  // ---- single-buffered pipeline registers ----
  float4 sS0, sS1, sE0, sE1;
  float sv[24], sd[4], smk[4], sdir[12];
  float acc[8];

  auto issueS = [&](int ebase) {
    const float* sp = S + ((size_t)(ebase + col16)) * 32 + kc;
    sS0 = *reinterpret_cast<const float4*>(sp);
    sS1 = *reinterpret_cast<const float4*>(sp + 4);
    const float* ep = EXPN + ((size_t)(ebase + col16)) * 20;
    if (c < 2) {
      sE0 = *reinterpret_cast<const float4*>(ep + kc);
      sE1 = *reinterpret_cast<const float4*>(ep + kc + 4);
    } else if (c == 2) {
      sE0 = *reinterpret_cast<const float4*>(ep + 16);
      sE1 = make_float4(1.f, 0.f, 0.f, 0.f);      // k=20 slot = 1 -> +br
    } else {
      sE0 = make_float4(0.f, 0.f, 0.f, 0.f);
      sE1 = make_float4(0.f, 0.f, 0.f, 0.f);
    }
  };

  auto issueV = [&](int ebase) {
    #pragma unroll
    for (int r = 0; r < 4; ++r) {
      int er = ebase + (c << 2) + r;
      sd[r]  = DIST[er];
      smk[r] = MASK[er];
      sdir[3*r+0] = DIR[3*er+0];
      sdir[3*r+1] = DIR[3*er+1];
      sdir[3*r+2] = DIR[3*er+2];
      const float* vp = V + (size_t)er * 96 + col16;
      #pragma unroll
      for (int t = 0; t < 2; ++t)
        #pragma unroll
        for (int ax = 0; ax < 3; ++ax)
          sv[(r*2 + t)*3 + ax] = vp[ax*32 + t*16];
    }
  };

  // computes the currently-staged iteration, prefetches ebNext
  auto body = [&](int ebNext) {
    bf16x8 bs, ae;
    bs[0]=f2bf(sS0.x); bs[1]=f2bf(sS0.y); bs[2]=f2bf(sS0.z); bs[3]=f2bf(sS0.w);
    bs[4]=f2bf(sS1.x); bs[5]=f2bf(sS1.y); bs[6]=f2bf(sS1.z); bs[7]=f2bf(sS1.w);
    ae[0]=f2bf(sE0.x); ae[1]=f2bf(sE0.y); ae[2]=f2bf(sE0.z); ae[3]=f2bf(sE0.w);
    ae[4]=f2bf(sE1.x); ae[5]=f2bf(sE1.y); ae[6]=f2bf(sE1.z); ae[7]=f2bf(sE1.w);
    issueS(ebNext);   // S/EXPN consumed -> immediately re-issue for next iter

    const f32x4 z = {0.f, 0.f, 0.f, 0.f};
    // right branch (independent of h chain; bias via k=20)
    f32x4 rA0 = __builtin_amdgcn_mfma_f32_16x16x32_bf16(ae, ldsfrag(&wlds[ 8][l<<2]), z, 0,0,0);
    f32x4 rA1 = __builtin_amdgcn_mfma_f32_16x16x32_bf16(ae, ldsfrag(&wlds[ 9][l<<2]), z, 0,0,0);
    f32x4 rB0 = __builtin_amdgcn_mfma_f32_16x16x32_bf16(ae, ldsfrag(&wlds[10][l<<2]), z, 0,0,0);
    f32x4 rB1 = __builtin_amdgcn_mfma_f32_16x16x32_bf16(ae, ldsfrag(&wlds[11][l<<2]), z, 0,0,0);
    f32x4 rC0 = __builtin_amdgcn_mfma_f32_16x16x32_bf16(ae, ldsfrag(&wlds[12][l<<2]), z, 0,0,0);
    f32x4 rC1 = __builtin_amdgcn_mfma_f32_16x16x32_bf16(ae, ldsfrag(&wlds[13][l<<2]), z, 0,0,0);

    // hT: D row = feature, col = edge  -> lane-local h row per edge
    f32x4 h0 = __builtin_amdgcn_mfma_f32_16x16x32_bf16(w1a0, bs, b1a, 0,0,0);
    f32x4 h1 = __builtin_amdgcn_mfma_f32_16x16x32_bf16(w1a1, bs, b1b, 0,0,0);

    float wr_[4];
    #pragma unroll
    for (int r = 0; r < 4; ++r) {
      float wv = 0.f;
      if (sd[r] < 5.f)
        wv = smk[r] * 0.5f * (__cosf(0.62831853071795865f * sd[r]) + 1.f);
      wr_[r] = wv;
    }

    bf16x8 ah;   // A-frag of h under pi(c,j)
    #pragma unroll
    for (int j = 0; j < 4; ++j) {
      float x = h0[j]; x = __fdividef(x, 1.f + __expf(-x)); ah[j] = f2bf(x);
    }
    #pragma unroll
    for (int j = 0; j < 4; ++j) {
      float x = h1[j]; x = __fdividef(x, 1.f + __expf(-x)); ah[4+j] = f2bf(x);
    }

    #pragma unroll
    for (int tt = 0; tt < 2; ++tt) {
      f32x4 lA = __builtin_amdgcn_mfma_f32_16x16x32_bf16(ah, ldsfrag(&wlds[2+tt][l<<2]), z, 0,0,0);
      f32x4 lB = __builtin_amdgcn_mfma_f32_16x16x32_bf16(ah, ldsfrag(&wlds[4+tt][l<<2]), z, 0,0,0);
      f32x4 lC = __builtin_amdgcn_mfma_f32_16x16x32_bf16(ah, ldsfrag(&wlds[6+tt][l<<2]), z, 0,0,0);
      f32x4 rA = tt ? rA1 : rA0;
      f32x4 rB = tt ? rB1 : rB0;
      f32x4 rC = tt ? rC1 : rC0;
      #pragma unroll
      for (int r = 0; r < 4; ++r) {
        float la = lA[r] + b2v[tt];
        float lb = lB[r] + b2v[2+tt];
        float lc = lC[r] + b2v[4+tt];
        float ga = wr_[r] * la * rA[r];
        float gb = wr_[r] * lb * rB[r];
        float gc = wr_[r] * lc * rC[r];
        acc[tt] += gb;
        acc[2+tt] = fmaf(sv[(r*2+tt)*3+0], ga, fmaf(sdir[3*r+0], gc, acc[2+tt]));
        acc[4+tt] = fmaf(sv[(r*2+tt)*3+1], ga, fmaf(sdir[3*r+1], gc, acc[4+tt]));
        acc[6+tt] = fmaf(sv[(r*2+tt)*3+2], ga, fmaf(sdir[3*r+2], gc, acc[6+tt]));
      }
    }
    issueV(ebNext);   // V consumed -> re-issue for next iter (full-iter coverage)
  };

  const int nbase = blockIdx.x * NPB + (wid << 2);
  int n0 = nbase; if (n0 >= n_nodes) n0 = n_nodes - 1;
  issueS(n0 << 5);
  issueV(n0 << 5);

  #pragma unroll 1
  for (int i = 0; i < 4; ++i) {
    int n = nbase + i; if (n >= n_nodes) n = n_nodes - 1;
    int nn = n + 1; if (i == 3 || nn >= n_nodes) nn = n;
    const int eb1 = (n << 5) + 16;

    #pragma unroll
    for (int q = 0; q < 8; ++q) acc[q] = 0.f;

    body(eb1);        // compute (n, eg0), prefetch (n, eg1)
    body(nn << 5);    // compute (n, eg1), prefetch (nn, eg0)

    #pragma unroll
    for (int q = 0; q < 8; ++q) {
      acc[q] += __shfl_xor(acc[q], 16);
      acc[q] += __shfl_xor(acc[q], 32);
    }
    if (l < 16) {
      float* os = OUT + (size_t)n * 32;
      os[col16]      = acc[0];
      os[16 + col16] = acc[1];
      float* ov = OUT + (size_t)n_nodes * 32 + (size_t)n * 96;
      ov[     col16] = acc[2]; ov[16 + col16] = acc[3];
      ov[32 + col16] = acc[4]; ov[48 + col16] = acc[5];
      ov[64 + col16] = acc[6]; ov[80 + col16] = acc[7];
    }
  }
}

extern "C" void kernel_launch(void* const* d_in, const int* in_sizes, int n_in,
                              void* d_out, int out_size, void* d_ws, size_t ws_size,
                              hipStream_t stream) {
  const float* S    = (const float*)d_in[0];
  const float* V    = (const float*)d_in[1];
  const float* EXPN = (const float*)d_in[2];
  const float* DIR  = (const float*)d_in[3];
  const float* MASK = (const float*)d_in[4];
  const float* DIST = (const float*)d_in[5];
  const float* W1   = (const float*)d_in[6];
  const float* B1   = (const float*)d_in[7];
  const float* W2   = (const float*)d_in[8];
  const float* B2   = (const float*)d_in[9];
  const float* WR   = (const float*)d_in[10];
  const float* BR   = (const float*)d_in[11];
  float* OUT = (float*)d_out;

  const int n_nodes = in_sizes[0] / 1024;            // 30000
  const int grid = (n_nodes + NPB - 1) / NPB;        // 1875

  hipLaunchKernelGGL(deepdft_v3, dim3(grid), dim3(256), 0, stream,
                     S, V, EXPN, DIR, MASK, DIST, W1, B1, W2, B2, WR, BR,
                     OUT, n_nodes);
}